// Round 8
// baseline (87.914 us; speedup 1.0000x reference)
//
#include <hip/hip_runtime.h>
#include <math.h>

#define NQ 10
typedef float v2f __attribute__((ext_vector_type(2)));

#if defined(__has_builtin)
#if __has_builtin(__builtin_amdgcn_permlane16_swap) && __has_builtin(__builtin_amdgcn_permlane32_swap)
#define HAVE_PL 1
#endif
#endif

template<int CTRL>
__device__ __forceinline__ float dppf(float x) {
    return __int_as_float(__builtin_amdgcn_update_dpp(
        __float_as_int(x), __float_as_int(x), CTRL, 0xF, 0xF, true));
}
template<int OFS>
__device__ __forceinline__ float swzf(float x) {
    return __int_as_float(__builtin_amdgcn_ds_swizzle(__float_as_int(x), OFS));
}
__device__ __forceinline__ float bperm(int idx, float x) {
    return __int_as_float(__builtin_amdgcn_ds_bpermute(idx, __float_as_int(x)));
}

// partner on lane-bit P for P=0..3 (VALU DPP except P=2 which is ds_swizzle)
template<int P>
__device__ __forceinline__ float partner1(float x) {
    if constexpr (P == 0) return dppf<0xB1>(x);        // quad_perm xor1
    else if constexpr (P == 1) return dppf<0x4E>(x);   // quad_perm xor2
    else if constexpr (P == 2) return swzf<0x101F>(x); // ds_swizzle xor4
    else return dppf<0x128>(x);                        // row_ror:8 = xor8
}
template<int P>
__device__ __forceinline__ v2f partner2(v2f v) {
    v2f r; r.x = partner1<P>(v.x); r.y = partner1<P>(v.y); return r;
}

// block swap on lane-bit P (P=4 or 5): returns {v0, v1} = pair members with bit P = 0 / 1
// CDNA4 V_PERMLANE16_SWAP_B32: DST.row[1]<->SRC.row[0], DST.row[3]<->SRC.row[2]
// => with DST=SRC=x: result[0][i] = x[i & ~16] (V0), result[1][i] = x[i | 16] (V1).
// V_PERMLANE32_SWAP_B32: DST.row[2:3]<->SRC.row[0:1] => result[0]=V0(bit5), result[1]=V1.
struct FPair { float v0, v1; };
template<int P>
__device__ __forceinline__ FPair blkswap1(float x, int lane) {
    FPair o;
#ifdef HAVE_PL
    if constexpr (P == 4) {
        auto r = __builtin_amdgcn_permlane16_swap(__float_as_uint(x), __float_as_uint(x), false, false);
        o.v0 = __uint_as_float(r[0]);
        o.v1 = __uint_as_float(r[1]);
    } else {
        auto r = __builtin_amdgcn_permlane32_swap(__float_as_uint(x), __float_as_uint(x), false, false);
        o.v0 = __uint_as_float(r[0]);
        o.v1 = __uint_as_float(r[1]);
    }
#else
    const float p = (P == 4) ? swzf<0x401F>(x) : bperm((lane ^ 32) << 2, x);
    const bool hi = (lane >> P) & 1;
    o.v0 = hi ? p : x;
    o.v1 = hi ? x : p;
#endif
    return o;
}
struct VPair { v2f V0, V1; };
template<int P>
__device__ __forceinline__ VPair blkswap2(v2f x, int lane) {
    const FPair a = blkswap1<P>(x.x, lane);
    const FPair b = blkswap1<P>(x.y, lane);
    VPair o;
    o.V0 = (v2f){a.v0, b.v0};
    o.V1 = (v2f){a.v1, b.v1};
    return o;
}
template<int P>
__device__ __forceinline__ float blkadd(float x, int lane) {   // x + partner (reduction)
    const FPair o = blkswap1<P>(x, lane);
    return o.v0 + o.v1;
}

// ---- gate bodies ----
// full complex gate on lane-bit P=4|5, per-lane row coeffs e=(er,ei), f=(fr,fi): new = e*V0 + f*V1
template<int P>
__device__ __forceinline__ void gate_blk_full(v2f (&Sr)[8], v2f (&Si)[8], int lane,
                                              float er, float ei, float fr, float fi) {
#pragma unroll
    for (int k = 0; k < 8; ++k) {
        const VPair R = blkswap2<P>(Sr[k], lane);
        const VPair I = blkswap2<P>(Si[k], lane);
        Sr[k] = er * R.V0 - ei * I.V0 + fr * R.V1 - fi * I.V1;
        Si[k] = er * I.V0 + ei * R.V0 + fr * I.V1 + fi * R.V1;
    }
}
// real gate on lane-bit P=4|5: new = e*V0 + f*V1
template<int P>
__device__ __forceinline__ void gate_blk_real(v2f (&Sr)[8], v2f (&Si)[8], int lane,
                                              float e, float f) {
#pragma unroll
    for (int k = 0; k < 8; ++k) {
        const VPair R = blkswap2<P>(Sr[k], lane);
        const VPair I = blkswap2<P>(Si[k], lane);
        Sr[k] = e * R.V0 + f * R.V1;
        Si[k] = e * I.V0 + f * I.V1;
    }
}
// full complex gate on lane-bit P=0..3, per-lane diag/offdiag coeffs
template<int P>
__device__ __forceinline__ void gate_dpp_full(v2f (&Sr)[8], v2f (&Si)[8],
                                              float dr, float di, float orr, float oii) {
#pragma unroll
    for (int k = 0; k < 8; ++k) {
        const v2f mr = Sr[k], mi = Si[k];
        const v2f pr = partner2<P>(mr);
        const v2f pi = partner2<P>(mi);
        Sr[k] = dr * mr - di * mi + orr * pr - oii * pi;
        Si[k] = dr * mi + di * mr + orr * pi + oii * pr;
    }
}
// real CRY-style gate on lane-bit P=0..3
template<int P>
__device__ __forceinline__ void gate_dpp_real(v2f (&Sr)[8], v2f (&Si)[8],
                                              float cl, float sgn) {
#pragma unroll
    for (int k = 0; k < 8; ++k) {
        const v2f pr = partner2<P>(Sr[k]);
        const v2f pi = partner2<P>(Si[k]);
        Sr[k] = cl * Sr[k] + sgn * pr;
        Si[k] = cl * Si[k] + sgn * pi;
    }
}
// complex 2x2 on an in-register pair, scalar coeffs
__device__ __forceinline__ void u3_pair(v2f& a0r, v2f& a0i, v2f& a1r, v2f& a1i,
                                        float u00r, float u00i, float u01r, float u01i,
                                        float u10r, float u10i, float u11r, float u11i) {
    v2f n0r = u00r * a0r - u00i * a0i + u01r * a1r - u01i * a1i;
    v2f n0i = u00r * a0i + u00i * a0r + u01r * a1i + u01i * a1r;
    v2f n1r = u10r * a0r - u10i * a0i + u11r * a1r - u11i * a1i;
    v2f n1i = u10r * a0i + u10i * a0r + u11r * a1i + u11i * a1r;
    a0r = n0r; a0i = n0i; a1r = n1r; a1i = n1i;
}
__device__ __forceinline__ void ry_pair(v2f& a0r, v2f& a0i, v2f& a1r, v2f& a1i,
                                        float c, float s) {
    v2f n0r = c * a0r - s * a1r;
    v2f n0i = c * a0i - s * a1i;
    v2f n1r = s * a0r + c * a1r;
    v2f n1i = s * a0i + c * a1i;
    a0r = n0r; a0i = n0i; a1r = n1r; a1i = n1i;
}
__device__ __forceinline__ void cmul(float& xr, float& xi, float br, float bi) {
    const float nr = xr * br - xi * bi;
    const float ni = xr * bi + xi * br;
    xr = nr; xi = ni;
}

// plus-reduction over lane bits FROM..5
template<int FROM>
__device__ __forceinline__ float plus_reduce(float x, int lane) {
    if constexpr (FROM <= 0) x += dppf<0xB1>(x);
    if constexpr (FROM <= 1) x += dppf<0x4E>(x);
    if constexpr (FROM <= 2) x += swzf<0x101F>(x);
    if constexpr (FROM <= 3) x += dppf<0x128>(x);
    if constexpr (FROM <= 4) x = blkadd<4>(x, lane);
    x = blkadd<5>(x, lane);
    return x;
}

// ======================= precompute =======================
// d_ws float layout:
//  [0..79]    U3_0 rows as float2 by (q, j): idx (q*4+j)*2 ; j: 0=(00r,01r) 1=(00i,01i) 2=(10r,11r) 3=(10i,11i)
//  [80..97]   CRY_0 e=0..8: (c,s) at 80+2e
//  [98..99]   CRY_1 e=9: (c,s)
//  [100..179] A_q = U3_1(q), 8 floats (00r,00i,01r,01i,10r,10i,11r,11i) at 100+8q
//  [180..259] B_q: q=0: A_0*RY(th_cry0_e9); q>=1: RY(th_cry1_e(q-1))*A_q ; at 180+8q
__device__ __forceinline__ void makeU3(float phi, float theta, float omega, float* u) {
    const float ct = cosf(0.5f * theta), st = sinf(0.5f * theta);
    const float apo = 0.5f * (phi + omega), amo = 0.5f * (phi - omega);
    const float capo = cosf(apo), sapo = sinf(apo);
    const float camo = cosf(amo), samo = sinf(amo);
    u[0] =  capo * ct;  u[1] = -sapo * ct;   // U00
    u[2] = -camo * st;  u[3] = -samo * st;   // U01
    u[4] =  camo * st;  u[5] = -samo * st;   // U10
    u[6] =  capo * ct;  u[7] =  sapo * ct;   // U11
}

__global__ void precompute(const float* __restrict__ w, float* __restrict__ cw) {
    const int t = threadIdx.x;
    if (t < 10) {                       // U3_0 rows, float2-by-(q,j)
        float u[8];
        makeU3(w[t * 3], w[t * 3 + 1], w[t * 3 + 2], u);
        float* p = cw + t * 8;
        p[0] = u[0]; p[1] = u[2];       // (00r, 01r)
        p[2] = u[1]; p[3] = u[3];       // (00i, 01i)
        p[4] = u[4]; p[5] = u[6];       // (10r, 11r)
        p[6] = u[5]; p[7] = u[7];       // (10i, 11i)
    } else if (t < 20) {                // A_q = U3_1(q)
        const int q = t - 10;
        float u[8];
        makeU3(w[40 + q * 3], w[40 + q * 3 + 1], w[40 + q * 3 + 2], u);
        float* p = cw + 100 + q * 8;
        for (int i = 0; i < 8; ++i) p[i] = u[i];
    } else if (t < 29) {                // CRY_0 e=0..8
        const int e = t - 20;
        const float th = 0.5f * w[30 + e];
        cw[80 + 2 * e] = cosf(th);
        cw[81 + 2 * e] = sinf(th);
    } else if (t == 29) {               // CRY_1 e=9
        const float th = 0.5f * w[79];
        cw[98] = cosf(th);
        cw[99] = sinf(th);
    } else if (t < 40) {                // B_q
        const int q = t - 30;
        float u[8];
        makeU3(w[40 + q * 3], w[40 + q * 3 + 1], w[40 + q * 3 + 2], u);
        float* p = cw + 180 + q * 8;
        if (q == 0) {                   // B_0 = A_0 * RY(th_cry0_e9)
            const float th = 0.5f * w[39];
            const float ct = cosf(th), st = sinf(th);
            p[0] = u[0] * ct + u[2] * st;  p[1] = u[1] * ct + u[3] * st;
            p[2] = u[2] * ct - u[0] * st;  p[3] = u[3] * ct - u[1] * st;
            p[4] = u[4] * ct + u[6] * st;  p[5] = u[5] * ct + u[7] * st;
            p[6] = u[6] * ct - u[4] * st;  p[7] = u[7] * ct - u[5] * st;
        } else {                        // B_q = RY(th_cry1_e(q-1)) * A_q
            const float th = 0.5f * w[70 + (q - 1)];
            const float ct = cosf(th), st = sinf(th);
            p[0] = ct * u[0] - st * u[4];  p[1] = ct * u[1] - st * u[5];
            p[2] = ct * u[2] - st * u[6];  p[3] = ct * u[3] - st * u[7];
            p[4] = st * u[0] + ct * u[4];  p[5] = st * u[1] + ct * u[5];
            p[6] = st * u[2] + ct * u[6];  p[7] = st * u[3] + ct * u[7];
        }
    }
}

#define LOADM(P, base) \
    const float P##00r = cf[(base) + 0], P##00i = cf[(base) + 1], \
                P##01r = cf[(base) + 2], P##01i = cf[(base) + 3], \
                P##10r = cf[(base) + 4], P##10i = cf[(base) + 5], \
                P##11r = cf[(base) + 6], P##11i = cf[(base) + 7];

// State layout per wave (one batch element per wave):
//   global index i[9:0], qubit q at bit p = 9-q.
//   lane = i[5:0] (qubits 4..9 on lane bits 5..0), k = i[8:6] (qubits 3,2,1 on k bits 0,1,2),
//   v2f component j = i[9] (qubit 0).
__global__ __launch_bounds__(256) void qsim(const float* __restrict__ in,
                                            const float* __restrict__ cf,
                                            float* __restrict__ out, int B) {
    __shared__ float tsh[4 * 40];
    const int lane = threadIdx.x & 63;
    const int wave = threadIdx.x >> 6;
    int b = blockIdx.x * 4 + wave;
    b = __builtin_amdgcn_readfirstlane(b);
    if (b >= B) return;

    // ---- distributed input fold: lane = q*4 + j computes t-component j of qubit q ----
    if (lane < 40) {
        const int q = lane >> 2;
        float x = in[b * NQ + q];
        x = fminf(fmaxf(x, 0.0f), 1.0f);
        const float a = 0.5f * 3.14159265358979323846f * x;
        const float ca = __cosf(a), sa = __sinf(a);
        const float M0 = cf[lane * 2], M1 = cf[lane * 2 + 1];   // vector load (lane-varying)
        tsh[wave * 40 + lane] = M0 * ca + M1 * sa;
    }
    const int base = wave * 40;

    // lane-bit amplitude chain (qubit 9-j on lane bit j), complex
    float wr, wi;
    {
        const int bit = lane & 1;
        const float2 v = *(const float2*)&tsh[base + 9 * 4 + (bit << 1)];
        wr = v.x; wi = v.y;
    }
#pragma unroll
    for (int j = 1; j < 6; ++j) {
        const int bit = (lane >> j) & 1;
        const float2 v = *(const float2*)&tsh[base + (9 - j) * 4 + (bit << 1)];
        cmul(wr, wi, v.x, v.y);
    }
    // k-qubit (1,2,3) and comp-qubit (0) t values — uniform broadcast reads
    const float4 T0 = *(const float4*)&tsh[base + 0];    // q0: t0r,t0i,t1r,t1i
    const float4 T1 = *(const float4*)&tsh[base + 4];
    const float4 T2 = *(const float4*)&tsh[base + 8];
    const float4 T3 = *(const float4*)&tsh[base + 12];

    // k-products: k = b1*4 + b2*2 + b3 (qubit1=k bit2, qubit2=k bit1, qubit3=k bit0)
    float vr[4], vi[4];
    { float r = T1.x, i2 = T1.y; vr[0] = r * T2.x - i2 * T2.y; vi[0] = r * T2.y + i2 * T2.x;
                                  vr[1] = r * T2.z - i2 * T2.w; vi[1] = r * T2.w + i2 * T2.z; }
    { float r = T1.z, i2 = T1.w; vr[2] = r * T2.x - i2 * T2.y; vi[2] = r * T2.y + i2 * T2.x;
                                  vr[3] = r * T2.z - i2 * T2.w; vi[3] = r * T2.w + i2 * T2.z; }
    v2f Sr[8], Si[8];
    const v2f T0r = {T0.x, T0.z};
    const v2f T0i = {T0.y, T0.w};
#pragma unroll
    for (int k = 0; k < 8; ++k) {
        const int hv = k >> 1;               // b1*2 + b2
        const float t3r = (k & 1) ? T3.z : T3.x;
        const float t3i = (k & 1) ? T3.w : T3.y;
        float kr = vr[hv] * t3r - vi[hv] * t3i;
        float ki = vr[hv] * t3i + vi[hv] * t3r;
        cmul(kr, ki, wr, wi);                // fold lane chain
        Sr[k] = kr * T0r - ki * T0i;
        Si[k] = kr * T0i + ki * T0r;
    }

    // ===== CRY_0 ring, e = 0..8 =====
    {   // e0: ctrl q0 (comp), tgt q1 (k bit2)
        const float c = cf[80], s = cf[81];
        const v2f cv = {1.0f, c};
        const v2f sv = {0.0f, s};
#pragma unroll
        for (int k0 = 0; k0 < 4; ++k0) {
            const int k1 = k0 | 4;
            v2f n0r = cv * Sr[k0] - sv * Sr[k1];
            v2f n0i = cv * Si[k0] - sv * Si[k1];
            v2f n1r = sv * Sr[k0] + cv * Sr[k1];
            v2f n1i = sv * Si[k0] + cv * Si[k1];
            Sr[k0] = n0r; Si[k0] = n0i; Sr[k1] = n1r; Si[k1] = n1i;
        }
    }
    {   // e1: ctrl q1 (k bit2), tgt q2 (k bit1)
        const float c = cf[82], s = cf[83];
        ry_pair(Sr[4], Si[4], Sr[6], Si[6], c, s);
        ry_pair(Sr[5], Si[5], Sr[7], Si[7], c, s);
    }
    {   // e2: ctrl q2 (k bit1), tgt q3 (k bit0)
        const float c = cf[84], s = cf[85];
        ry_pair(Sr[2], Si[2], Sr[3], Si[3], c, s);
        ry_pair(Sr[6], Si[6], Sr[7], Si[7], c, s);
    }
    {   // e3: ctrl q3 (k bit0) -> odd k only; tgt q4 (lane bit5), block form
        const float c = cf[86], s = cf[87];
        const bool hi = (lane >> 5) & 1;
        const float e = hi ? s : c;
        const float f = hi ? c : -s;
#pragma unroll
        for (int k = 1; k < 8; k += 2) {
            const VPair R = blkswap2<5>(Sr[k], lane);
            const VPair I = blkswap2<5>(Si[k], lane);
            Sr[k] = e * R.V0 + f * R.V1;
            Si[k] = e * I.V0 + f * I.V1;
        }
    }
    {   // e4: ctrl q4 (lane bit5), tgt q5 (lane bit4), block form
        const float c = cf[88], s = cf[89];
        const bool ctrl = (lane >> 5) & 1;
        const bool hi = (lane >> 4) & 1;
        const float e = ctrl ? (hi ? s : c) : (hi ? 0.0f : 1.0f);
        const float f = ctrl ? (hi ? c : -s) : (hi ? 1.0f : 0.0f);
        gate_blk_real<4>(Sr, Si, lane, e, f);
    }
    {   // e5: ctrl lane bit4, tgt lane bit3 (DPP)
        const float c = cf[90], s = cf[91];
        const bool ctrl = (lane >> 4) & 1;
        const float cl = ctrl ? c : 1.0f;
        const float sl = ctrl ? s : 0.0f;
        const float sgn = ((lane >> 3) & 1) ? sl : -sl;
        gate_dpp_real<3>(Sr, Si, cl, sgn);
    }
    {   // e6: ctrl lane bit3, tgt lane bit2 (swizzle)
        const float c = cf[92], s = cf[93];
        const bool ctrl = (lane >> 3) & 1;
        const float cl = ctrl ? c : 1.0f;
        const float sl = ctrl ? s : 0.0f;
        const float sgn = ((lane >> 2) & 1) ? sl : -sl;
        gate_dpp_real<2>(Sr, Si, cl, sgn);
    }
    {   // e7: ctrl lane bit2, tgt lane bit1 (DPP)
        const float c = cf[94], s = cf[95];
        const bool ctrl = (lane >> 2) & 1;
        const float cl = ctrl ? c : 1.0f;
        const float sl = ctrl ? s : 0.0f;
        const float sgn = ((lane >> 1) & 1) ? sl : -sl;
        gate_dpp_real<1>(Sr, Si, cl, sgn);
    }
    {   // e8: ctrl lane bit1, tgt lane bit0 (DPP)
        const float c = cf[96], s = cf[97];
        const bool ctrl = (lane >> 1) & 1;
        const float cl = ctrl ? c : 1.0f;
        const float sl = ctrl ? s : 0.0f;
        const float sgn = (lane & 1) ? sl : -sl;
        gate_dpp_real<0>(Sr, Si, cl, sgn);
    }

    // ===== F0 = U3_1(0) * CRY_0(9): ctrl q9 (lane bit0), tgt q0 (comp) =====
    {
        LOADM(A, 100); LOADM(Bm, 180);
        const bool ctrl = lane & 1;
        const float M00r = ctrl ? Bm00r : A00r, M00i = ctrl ? Bm00i : A00i;
        const float M01r = ctrl ? Bm01r : A01r, M01i = ctrl ? Bm01i : A01i;
        const float M10r = ctrl ? Bm10r : A10r, M10i = ctrl ? Bm10i : A10i;
        const float M11r = ctrl ? Bm11r : A11r, M11i = ctrl ? Bm11i : A11i;
        const v2f Dr = {M00r, M11r}, Di = {M00i, M11i};
        const v2f Or = {M01r, M10r}, Oi = {M01i, M10i};
#pragma unroll
        for (int k = 0; k < 8; ++k) {
            const v2f Ar = Sr[k], Ai = Si[k];
            const v2f Br = Ar.yx, Bi = Ai.yx;
            Sr[k] = Dr * Ar - Di * Ai + Or * Br - Oi * Bi;
            Si[k] = Dr * Ai + Di * Ar + Or * Bi + Oi * Br;
        }
    }
    // ===== F1 = CRY_1(0) * U3_1(1): ctrl q0 (comp), tgt q1 (k bit2) =====
    {
        LOADM(A, 108); LOADM(Bm, 188);
        const v2f u00r = {A00r, Bm00r}, u00i = {A00i, Bm00i};
        const v2f u01r = {A01r, Bm01r}, u01i = {A01i, Bm01i};
        const v2f u10r = {A10r, Bm10r}, u10i = {A10i, Bm10i};
        const v2f u11r = {A11r, Bm11r}, u11i = {A11i, Bm11i};
#pragma unroll
        for (int k0 = 0; k0 < 4; ++k0) {
            const int k1 = k0 | 4;
            v2f n0r = u00r * Sr[k0] - u00i * Si[k0] + u01r * Sr[k1] - u01i * Si[k1];
            v2f n0i = u00r * Si[k0] + u00i * Sr[k0] + u01r * Si[k1] + u01i * Sr[k1];
            v2f n1r = u10r * Sr[k0] - u10i * Si[k0] + u11r * Sr[k1] - u11i * Si[k1];
            v2f n1i = u10r * Si[k0] + u10i * Sr[k0] + u11r * Si[k1] + u11i * Sr[k1];
            Sr[k0] = n0r; Si[k0] = n0i; Sr[k1] = n1r; Si[k1] = n1i;
        }
    }
    // ===== F2 = CRY_1(1) * U3_1(2): ctrl q1 (k bit2), tgt q2 (k bit1) =====
    {
        LOADM(A, 116); LOADM(Bm, 196);
        u3_pair(Sr[0], Si[0], Sr[2], Si[2], A00r, A00i, A01r, A01i, A10r, A10i, A11r, A11i);
        u3_pair(Sr[1], Si[1], Sr[3], Si[3], A00r, A00i, A01r, A01i, A10r, A10i, A11r, A11i);
        u3_pair(Sr[4], Si[4], Sr[6], Si[6], Bm00r, Bm00i, Bm01r, Bm01i, Bm10r, Bm10i, Bm11r, Bm11i);
        u3_pair(Sr[5], Si[5], Sr[7], Si[7], Bm00r, Bm00i, Bm01r, Bm01i, Bm10r, Bm10i, Bm11r, Bm11i);
    }
    // ===== F3 = CRY_1(2) * U3_1(3): ctrl q2 (k bit1), tgt q3 (k bit0) =====
    {
        LOADM(A, 124); LOADM(Bm, 204);
        u3_pair(Sr[0], Si[0], Sr[1], Si[1], A00r, A00i, A01r, A01i, A10r, A10i, A11r, A11i);
        u3_pair(Sr[4], Si[4], Sr[5], Si[5], A00r, A00i, A01r, A01i, A10r, A10i, A11r, A11i);
        u3_pair(Sr[2], Si[2], Sr[3], Si[3], Bm00r, Bm00i, Bm01r, Bm01i, Bm10r, Bm10i, Bm11r, Bm11i);
        u3_pair(Sr[6], Si[6], Sr[7], Si[7], Bm00r, Bm00i, Bm01r, Bm01i, Bm10r, Bm10i, Bm11r, Bm11i);
    }
    // ===== F4 = CRY_1(3) * U3_1(4): ctrl q3 (k bit0), tgt q4 (lane bit5), block form =====
    {
        LOADM(A, 132); LOADM(Bm, 212);
        const bool hi = (lane >> 5) & 1;
        const float eAr = hi ? A10r : A00r, eAi = hi ? A10i : A00i;
        const float fAr = hi ? A11r : A01r, fAi = hi ? A11i : A01i;
        const float eBr = hi ? Bm10r : Bm00r, eBi = hi ? Bm10i : Bm00i;
        const float fBr = hi ? Bm11r : Bm01r, fBi = hi ? Bm11i : Bm01i;
#pragma unroll
        for (int k = 0; k < 8; ++k) {
            const float er = (k & 1) ? eBr : eAr, ei = (k & 1) ? eBi : eAi;
            const float fr = (k & 1) ? fBr : fAr, fi = (k & 1) ? fBi : fAi;
            const VPair R = blkswap2<5>(Sr[k], lane);
            const VPair I = blkswap2<5>(Si[k], lane);
            Sr[k] = er * R.V0 - ei * I.V0 + fr * R.V1 - fi * I.V1;
            Si[k] = er * I.V0 + ei * R.V0 + fr * I.V1 + fi * R.V1;
        }
    }
    // ===== F5 = CRY_1(4) * U3_1(5): ctrl lane bit5, tgt lane bit4, block form =====
    {
        LOADM(A, 140); LOADM(Bm, 220);
        const bool ctrl = (lane >> 5) & 1;
        const bool hi = (lane >> 4) & 1;
        const float M00r = ctrl ? Bm00r : A00r, M00i = ctrl ? Bm00i : A00i;
        const float M01r = ctrl ? Bm01r : A01r, M01i = ctrl ? Bm01i : A01i;
        const float M10r = ctrl ? Bm10r : A10r, M10i = ctrl ? Bm10i : A10i;
        const float M11r = ctrl ? Bm11r : A11r, M11i = ctrl ? Bm11i : A11i;
        const float er = hi ? M10r : M00r, ei = hi ? M10i : M00i;
        const float fr = hi ? M11r : M01r, fi = hi ? M11i : M01i;
        gate_blk_full<4>(Sr, Si, lane, er, ei, fr, fi);
    }
    // ===== F6..F9: DPP / swizzle lane-bit gates =====
    {
        LOADM(A, 148); LOADM(Bm, 228);       // ctrl bit4, tgt bit3
        const bool ctrl = (lane >> 4) & 1;
        const bool hi = (lane >> 3) & 1;
        const float M00r = ctrl ? Bm00r : A00r, M00i = ctrl ? Bm00i : A00i;
        const float M01r = ctrl ? Bm01r : A01r, M01i = ctrl ? Bm01i : A01i;
        const float M10r = ctrl ? Bm10r : A10r, M10i = ctrl ? Bm10i : A10i;
        const float M11r = ctrl ? Bm11r : A11r, M11i = ctrl ? Bm11i : A11i;
        const float dr = hi ? M11r : M00r, di = hi ? M11i : M00i;
        const float orr = hi ? M10r : M01r, oii = hi ? M10i : M01i;
        gate_dpp_full<3>(Sr, Si, dr, di, orr, oii);
    }
    {
        LOADM(A, 156); LOADM(Bm, 236);       // ctrl bit3, tgt bit2
        const bool ctrl = (lane >> 3) & 1;
        const bool hi = (lane >> 2) & 1;
        const float M00r = ctrl ? Bm00r : A00r, M00i = ctrl ? Bm00i : A00i;
        const float M01r = ctrl ? Bm01r : A01r, M01i = ctrl ? Bm01i : A01i;
        const float M10r = ctrl ? Bm10r : A10r, M10i = ctrl ? Bm10i : A10i;
        const float M11r = ctrl ? Bm11r : A11r, M11i = ctrl ? Bm11i : A11i;
        const float dr = hi ? M11r : M00r, di = hi ? M11i : M00i;
        const float orr = hi ? M10r : M01r, oii = hi ? M10i : M01i;
        gate_dpp_full<2>(Sr, Si, dr, di, orr, oii);
    }
    {
        LOADM(A, 164); LOADM(Bm, 244);       // ctrl bit2, tgt bit1
        const bool ctrl = (lane >> 2) & 1;
        const bool hi = (lane >> 1) & 1;
        const float M00r = ctrl ? Bm00r : A00r, M00i = ctrl ? Bm00i : A00i;
        const float M01r = ctrl ? Bm01r : A01r, M01i = ctrl ? Bm01i : A01i;
        const float M10r = ctrl ? Bm10r : A10r, M10i = ctrl ? Bm10i : A10i;
        const float M11r = ctrl ? Bm11r : A11r, M11i = ctrl ? Bm11i : A11i;
        const float dr = hi ? M11r : M00r, di = hi ? M11i : M00i;
        const float orr = hi ? M10r : M01r, oii = hi ? M10i : M01i;
        gate_dpp_full<1>(Sr, Si, dr, di, orr, oii);
    }
    {
        LOADM(A, 172); LOADM(Bm, 252);       // ctrl bit1, tgt bit0
        const bool ctrl = (lane >> 1) & 1;
        const bool hi = lane & 1;
        const float M00r = ctrl ? Bm00r : A00r, M00i = ctrl ? Bm00i : A00i;
        const float M01r = ctrl ? Bm01r : A01r, M01i = ctrl ? Bm01i : A01i;
        const float M10r = ctrl ? Bm10r : A10r, M10i = ctrl ? Bm10i : A10i;
        const float M11r = ctrl ? Bm11r : A11r, M11i = ctrl ? Bm11i : A11i;
        const float dr = hi ? M11r : M00r, di = hi ? M11i : M00i;
        const float orr = hi ? M10r : M01r, oii = hi ? M10i : M01i;
        gate_dpp_full<0>(Sr, Si, dr, di, orr, oii);
    }
    // ===== CRY_1(9): ctrl q9 (lane bit0), tgt q0 (comp) =====
    {
        const float c = cf[98], s = cf[99];
        const bool ctrl = lane & 1;
        const float cl = ctrl ? c : 1.0f;
        const float sl = ctrl ? s : 0.0f;
        const v2f C2 = {cl, cl};
        const v2f S2 = {-sl, sl};
#pragma unroll
        for (int k = 0; k < 8; ++k) {
            const v2f Ar = Sr[k], Ai = Si[k];
            Sr[k] = C2 * Ar + S2 * Ar.yx;
            Si[k] = C2 * Ai + S2 * Ai.yx;
        }
    }

    // ===== measurement =====
    v2f P[8];
    float ptot = 0.0f, z0p = 0.0f, z1p = 0.0f, z2p = 0.0f, z3p = 0.0f;
#pragma unroll
    for (int k = 0; k < 8; ++k) {
        P[k] = Sr[k] * Sr[k] + Si[k] * Si[k];
        const float sk = P[k].x + P[k].y;
        ptot += sk;
        z0p += P[k].x - P[k].y;
        z1p += ((k >> 2) & 1) ? -sk : sk;   // qubit1 = k bit2
        z2p += ((k >> 1) & 1) ? -sk : sk;   // qubit2 = k bit1
        z3p += (k & 1) ? -sk : sk;          // qubit3 = k bit0
    }
    // Walsh chain on ptot for lane-bit qubits (qubit q at lane bit 9-q)
    float d0, d1, d2, d3, d4, d5;
    {
        float a = ptot, p;
        p = dppf<0xB1>(a);   d0 = a - p; a += p;
        p = dppf<0x4E>(a);   d1 = a - p; a += p;
        p = swzf<0x101F>(a); d2 = a - p; a += p;
        p = dppf<0x128>(a);  d3 = a - p; a += p;
        { const FPair o = blkswap1<4>(a, lane); d4 = o.v0 - o.v1; a = o.v0 + o.v1; }
        { const FPair o = blkswap1<5>(a, lane); d5 = o.v0 - o.v1; }
    }
    float z[NQ];
    z[0] = plus_reduce<0>(z0p, lane);
    z[1] = plus_reduce<0>(z1p, lane);
    z[2] = plus_reduce<0>(z2p, lane);
    z[3] = plus_reduce<0>(z3p, lane);
    z[4] = d5;                          // lane bit5
    z[5] = plus_reduce<5>(d4, lane);    // lane bit4
    z[6] = plus_reduce<4>(d3, lane);    // lane bit3
    z[7] = plus_reduce<3>(d2, lane);    // lane bit2
    z[8] = plus_reduce<2>(d1, lane);    // lane bit1
    z[9] = plus_reduce<1>(d0, lane);    // lane bit0

    if (lane == 0) {
#pragma unroll
        for (int q = 0; q < NQ; ++q) out[b * NQ + q] = z[q];
    }
}

extern "C" void kernel_launch(void* const* d_in, const int* in_sizes, int n_in,
                              void* d_out, int out_size, void* d_ws, size_t ws_size,
                              hipStream_t stream) {
    const float* inputs  = (const float*)d_in[0];
    const float* weights = (const float*)d_in[1];
    float* out = (float*)d_out;
    float* cw  = (float*)d_ws;          // 260 floats
    const int B = in_sizes[0] / NQ;

    precompute<<<1, 64, 0, stream>>>(weights, cw);
    qsim<<<(B + 3) / 4, 256, 0, stream>>>(inputs, cw, out, B);
}

// Round 9
// 82.349 us; speedup vs baseline: 1.0676x; 1.0676x over previous
//
#include <hip/hip_runtime.h>
#include <math.h>

#define NQ 10
typedef float v2f __attribute__((ext_vector_type(2)));

#if defined(__has_builtin)
#if __has_builtin(__builtin_amdgcn_permlane16_swap) && __has_builtin(__builtin_amdgcn_permlane32_swap)
#define HAVE_PL 1
#endif
#endif

template<int CTRL>
__device__ __forceinline__ float dppf(float x) {
    return __int_as_float(__builtin_amdgcn_update_dpp(
        __float_as_int(x), __float_as_int(x), CTRL, 0xF, 0xF, true));
}
template<int OFS>
__device__ __forceinline__ float swzf(float x) {
    return __int_as_float(__builtin_amdgcn_ds_swizzle(__float_as_int(x), OFS));
}
__device__ __forceinline__ float bperm(int idx, float x) {
    return __int_as_float(__builtin_amdgcn_ds_bpermute(idx, __float_as_int(x)));
}

// partner on lane-bit P for P=0..3 (VALU DPP except P=2 which is ds_swizzle)
template<int P>
__device__ __forceinline__ float partner1(float x) {
    if constexpr (P == 0) return dppf<0xB1>(x);        // quad_perm xor1
    else if constexpr (P == 1) return dppf<0x4E>(x);   // quad_perm xor2
    else if constexpr (P == 2) return swzf<0x101F>(x); // ds_swizzle xor4
    else return dppf<0x128>(x);                        // row_ror:8 = xor8
}
template<int P>
__device__ __forceinline__ v2f partner2(v2f v) {
    v2f r; r.x = partner1<P>(v.x); r.y = partner1<P>(v.y); return r;
}

// block swap on lane-bit P (P=4 or 5): returns {v0, v1} = pair members with bit P = 0 / 1
// CDNA4 V_PERMLANE16_SWAP_B32 with DST=SRC=x: result[0]=x[i&~16] (V0), result[1]=x[i|16] (V1).
// V_PERMLANE32_SWAP_B32: result[0]=x[i&~32] (V0), result[1]=x[i|32] (V1).
struct FPair { float v0, v1; };
template<int P>
__device__ __forceinline__ FPair blkswap1(float x, int lane) {
    FPair o;
#ifdef HAVE_PL
    if constexpr (P == 4) {
        auto r = __builtin_amdgcn_permlane16_swap(__float_as_uint(x), __float_as_uint(x), false, false);
        o.v0 = __uint_as_float(r[0]);
        o.v1 = __uint_as_float(r[1]);
    } else {
        auto r = __builtin_amdgcn_permlane32_swap(__float_as_uint(x), __float_as_uint(x), false, false);
        o.v0 = __uint_as_float(r[0]);
        o.v1 = __uint_as_float(r[1]);
    }
#else
    const float p = (P == 4) ? swzf<0x401F>(x) : bperm((lane ^ 32) << 2, x);
    const bool hi = (lane >> P) & 1;
    o.v0 = hi ? p : x;
    o.v1 = hi ? x : p;
#endif
    return o;
}
struct VPair { v2f V0, V1; };
template<int P>
__device__ __forceinline__ VPair blkswap2(v2f x, int lane) {
    const FPair a = blkswap1<P>(x.x, lane);
    const FPair b = blkswap1<P>(x.y, lane);
    VPair o;
    o.V0 = (v2f){a.v0, b.v0};
    o.V1 = (v2f){a.v1, b.v1};
    return o;
}
template<int P>
__device__ __forceinline__ float blkadd(float x, int lane) {   // x + partner (reduction)
    const FPair o = blkswap1<P>(x, lane);
    return o.v0 + o.v1;
}

// ---- gate bodies ----
template<int P>
__device__ __forceinline__ void gate_blk_full(v2f (&Sr)[8], v2f (&Si)[8], int lane,
                                              float er, float ei, float fr, float fi) {
#pragma unroll
    for (int k = 0; k < 8; ++k) {
        const VPair R = blkswap2<P>(Sr[k], lane);
        const VPair I = blkswap2<P>(Si[k], lane);
        Sr[k] = er * R.V0 - ei * I.V0 + fr * R.V1 - fi * I.V1;
        Si[k] = er * I.V0 + ei * R.V0 + fr * I.V1 + fi * R.V1;
    }
}
template<int P>
__device__ __forceinline__ void gate_blk_real(v2f (&Sr)[8], v2f (&Si)[8], int lane,
                                              float e, float f) {
#pragma unroll
    for (int k = 0; k < 8; ++k) {
        const VPair R = blkswap2<P>(Sr[k], lane);
        const VPair I = blkswap2<P>(Si[k], lane);
        Sr[k] = e * R.V0 + f * R.V1;
        Si[k] = e * I.V0 + f * I.V1;
    }
}
template<int P>
__device__ __forceinline__ void gate_dpp_full(v2f (&Sr)[8], v2f (&Si)[8],
                                              float dr, float di, float orr, float oii) {
#pragma unroll
    for (int k = 0; k < 8; ++k) {
        const v2f mr = Sr[k], mi = Si[k];
        const v2f pr = partner2<P>(mr);
        const v2f pi = partner2<P>(mi);
        Sr[k] = dr * mr - di * mi + orr * pr - oii * pi;
        Si[k] = dr * mi + di * mr + orr * pi + oii * pr;
    }
}
template<int P>
__device__ __forceinline__ void gate_dpp_real(v2f (&Sr)[8], v2f (&Si)[8],
                                              float cl, float sgn) {
#pragma unroll
    for (int k = 0; k < 8; ++k) {
        const v2f pr = partner2<P>(Sr[k]);
        const v2f pi = partner2<P>(Si[k]);
        Sr[k] = cl * Sr[k] + sgn * pr;
        Si[k] = cl * Si[k] + sgn * pi;
    }
}
__device__ __forceinline__ void u3_pair(v2f& a0r, v2f& a0i, v2f& a1r, v2f& a1i,
                                        float u00r, float u00i, float u01r, float u01i,
                                        float u10r, float u10i, float u11r, float u11i) {
    v2f n0r = u00r * a0r - u00i * a0i + u01r * a1r - u01i * a1i;
    v2f n0i = u00r * a0i + u00i * a0r + u01r * a1i + u01i * a1r;
    v2f n1r = u10r * a0r - u10i * a0i + u11r * a1r - u11i * a1i;
    v2f n1i = u10r * a0i + u10i * a0r + u11r * a1i + u11i * a1r;
    a0r = n0r; a0i = n0i; a1r = n1r; a1i = n1i;
}
__device__ __forceinline__ void ry_pair(v2f& a0r, v2f& a0i, v2f& a1r, v2f& a1i,
                                        float c, float s) {
    v2f n0r = c * a0r - s * a1r;
    v2f n0i = c * a0i - s * a1i;
    v2f n1r = s * a0r + c * a1r;
    v2f n1i = s * a0i + c * a1i;
    a0r = n0r; a0i = n0i; a1r = n1r; a1i = n1i;
}
__device__ __forceinline__ void cmul(float& xr, float& xi, float br, float bi) {
    const float nr = xr * br - xi * bi;
    const float ni = xr * bi + xi * br;
    xr = nr; xi = ni;
}

// plus-reduction over lane bits FROM..5
template<int FROM>
__device__ __forceinline__ float plus_reduce(float x, int lane) {
    if constexpr (FROM <= 0) x += dppf<0xB1>(x);
    if constexpr (FROM <= 1) x += dppf<0x4E>(x);
    if constexpr (FROM <= 2) x += swzf<0x101F>(x);
    if constexpr (FROM <= 3) x += dppf<0x128>(x);
    if constexpr (FROM <= 4) x = blkadd<4>(x, lane);
    x = blkadd<5>(x, lane);
    return x;
}

#define LOADM(P, base) \
    const float4 P##va = *(const float4*)&cs[(base)]; \
    const float4 P##vb = *(const float4*)&cs[(base) + 4]; \
    const float P##00r = P##va.x, P##00i = P##va.y, P##01r = P##va.z, P##01i = P##va.w, \
                P##10r = P##vb.x, P##10i = P##vb.y, P##11r = P##vb.z, P##11i = P##vb.w;

// Per-wave coefficient slice (cs[]) float layout — identical indices to R8's d_ws:
//  [0..79]    U3_0 rows as float2 by (q, j): (q*4+j)*2 ; j: 0=(00r,01r) 1=(00i,01i) 2=(10r,11r) 3=(10i,11i)
//  [80..97]   CRY_0 e=0..8: (c,s) at 80+2e
//  [98..99]   CRY_1 e=9: (c,s)
//  [100..179] A_q = U3_1(q), 8 floats at 100+8q
//  [180..259] B_q: q=0: A_0*RY(w39); q>=1: RY(w[70+q-1])*A_q ; at 180+8q

// State layout per wave (one batch element per wave):
//   global index i[9:0], qubit q at bit p = 9-q.
//   lane = i[5:0] (qubits 4..9 on lane bits 5..0), k = i[8:6] (qubits 3,2,1 on k bits 0,1,2),
//   v2f component j = i[9] (qubit 0).
__global__ __launch_bounds__(256) void qsim(const float* __restrict__ in,
                                            const float* __restrict__ w,
                                            float* __restrict__ out, int B) {
    __shared__ __attribute__((aligned(16))) float csh[4 * 272];
    __shared__ __attribute__((aligned(16))) float tsh[4 * 40];
    const int lane = threadIdx.x & 63;
    const int wave = threadIdx.x >> 6;
    int b = blockIdx.x * 4 + wave;
    b = __builtin_amdgcn_readfirstlane(b);
    if (b >= B) return;
    float* cs = csh + wave * 272;

    // ===== per-wave distributed coefficient generation =====
    // lanes 0..9: U3_0(q) row-format; 10..19: A_q=U3_1(q); 20..28: CRY_0 e (c,s);
    // 29: CRY_1 e9 (c,s); 40..49: B_q (recompute A_q + local CRY trig, no cross-lane).
    {
        const int q = (lane < 20) ? (lane % 10) : ((lane >= 40 && lane < 50) ? lane - 40 : 0);
        const int wb = (lane < 10) ? 3 * lane : 40 + 3 * q;
        const float phi = w[wb], theta = w[wb + 1], omega = w[wb + 2];
        float u0, u1, u2, u3, u4, u5, u6, u7;
        {
            const float ct = __cosf(0.5f * theta), st = __sinf(0.5f * theta);
            const float apo = 0.5f * (phi + omega), amo = 0.5f * (phi - omega);
            const float capo = __cosf(apo), sapo = __sinf(apo);
            const float camo = __cosf(amo), samo = __sinf(amo);
            u0 =  capo * ct;  u1 = -sapo * ct;   // U00
            u2 = -camo * st;  u3 = -samo * st;   // U01
            u4 =  camo * st;  u5 = -samo * st;   // U10
            u6 =  capo * ct;  u7 =  sapo * ct;   // U11
        }
        // CRY angle: lanes 20..28 -> w[30+e]; lane 29 -> w[79];
        // lane 40 -> w[39]; lanes 41..49 -> w[70+q-1]; others: harmless in-bounds dummy.
        const int cidx = (lane >= 20 && lane < 29) ? 30 + (lane - 20)
                       : (lane == 29) ? 79
                       : (lane == 40) ? 39
                       : 70 + (q - 1) + (q == 0 ? 1 : 0);   // q==0 non-B lanes -> 70 (dummy)
        const float th = 0.5f * w[cidx];
        const float c2 = __cosf(th), s2 = __sinf(th);
        if (lane >= 40 && lane < 50) {
            const bool r = (lane == 40);       // B_0 = A*RY (right); else B_q = RY*A (left)
            const float p0 = r ? (u0 * c2 + u2 * s2) : (c2 * u0 - s2 * u4);
            const float p1 = r ? (u1 * c2 + u3 * s2) : (c2 * u1 - s2 * u5);
            const float p2 = r ? (u2 * c2 - u0 * s2) : (c2 * u2 - s2 * u6);
            const float p3 = r ? (u3 * c2 - u1 * s2) : (c2 * u3 - s2 * u7);
            const float p4 = r ? (u4 * c2 + u6 * s2) : (s2 * u0 + c2 * u4);
            const float p5 = r ? (u5 * c2 + u7 * s2) : (s2 * u1 + c2 * u5);
            const float p6 = r ? (u6 * c2 - u4 * s2) : (s2 * u2 + c2 * u6);
            const float p7 = r ? (u7 * c2 - u5 * s2) : (s2 * u3 + c2 * u7);
            u0 = p0; u1 = p1; u2 = p2; u3 = p3; u4 = p4; u5 = p5; u6 = p6; u7 = p7;
        }
        if (lane < 10) {                       // U3_0 row format
            *(float4*)&cs[lane * 8]     = (float4){u0, u2, u1, u3};   // (00r,01r,00i,01i)
            *(float4*)&cs[lane * 8 + 4] = (float4){u4, u6, u5, u7};   // (10r,11r,10i,11i)
        } else if (lane < 20) {                // A_q
            *(float4*)&cs[100 + (lane - 10) * 8]     = (float4){u0, u1, u2, u3};
            *(float4*)&cs[100 + (lane - 10) * 8 + 4] = (float4){u4, u5, u6, u7};
        } else if (lane < 30) {                // CRY pairs
            const int off = (lane < 29) ? 80 + 2 * (lane - 20) : 98;
            *(float2*)&cs[off] = (float2){c2, s2};
        } else if (lane >= 40 && lane < 50) {  // B_q
            *(float4*)&cs[180 + q * 8]     = (float4){u0, u1, u2, u3};
            *(float4*)&cs[180 + q * 8 + 4] = (float4){u4, u5, u6, u7};
        }
    }

    // ---- distributed input fold: lane = q*4 + j computes t-component j of qubit q ----
    if (lane < 40) {
        const int q = lane >> 2;
        float x = in[b * NQ + q];
        x = fminf(fmaxf(x, 0.0f), 1.0f);
        const float a = 0.5f * 3.14159265358979323846f * x;
        const float ca = __cosf(a), sa = __sinf(a);
        const float M0 = cs[lane * 2], M1 = cs[lane * 2 + 1];
        tsh[wave * 40 + lane] = M0 * ca + M1 * sa;
    }
    const int base = wave * 40;

    // lane-bit amplitude chain (qubit 9-j on lane bit j), complex
    float wr, wi;
    {
        const int bit = lane & 1;
        const float2 v = *(const float2*)&tsh[base + 9 * 4 + (bit << 1)];
        wr = v.x; wi = v.y;
    }
#pragma unroll
    for (int j = 1; j < 6; ++j) {
        const int bit = (lane >> j) & 1;
        const float2 v = *(const float2*)&tsh[base + (9 - j) * 4 + (bit << 1)];
        cmul(wr, wi, v.x, v.y);
    }
    // k-qubit (1,2,3) and comp-qubit (0) t values — uniform broadcast reads
    const float4 T0 = *(const float4*)&tsh[base + 0];
    const float4 T1 = *(const float4*)&tsh[base + 4];
    const float4 T2 = *(const float4*)&tsh[base + 8];
    const float4 T3 = *(const float4*)&tsh[base + 12];

    float vr[4], vi[4];
    { float r = T1.x, i2 = T1.y; vr[0] = r * T2.x - i2 * T2.y; vi[0] = r * T2.y + i2 * T2.x;
                                  vr[1] = r * T2.z - i2 * T2.w; vi[1] = r * T2.w + i2 * T2.z; }
    { float r = T1.z, i2 = T1.w; vr[2] = r * T2.x - i2 * T2.y; vi[2] = r * T2.y + i2 * T2.x;
                                  vr[3] = r * T2.z - i2 * T2.w; vi[3] = r * T2.w + i2 * T2.z; }
    v2f Sr[8], Si[8];
    const v2f T0r = {T0.x, T0.z};
    const v2f T0i = {T0.y, T0.w};
#pragma unroll
    for (int k = 0; k < 8; ++k) {
        const int hv = k >> 1;
        const float t3r = (k & 1) ? T3.z : T3.x;
        const float t3i = (k & 1) ? T3.w : T3.y;
        float kr = vr[hv] * t3r - vi[hv] * t3i;
        float ki = vr[hv] * t3i + vi[hv] * t3r;
        cmul(kr, ki, wr, wi);
        Sr[k] = kr * T0r - ki * T0i;
        Si[k] = kr * T0i + ki * T0r;
    }

    // ===== CRY_0 ring, e = 0..8 =====
    {   // e0: ctrl q0 (comp), tgt q1 (k bit2)
        const float2 C = *(const float2*)&cs[80];
        const v2f cv = {1.0f, C.x};
        const v2f sv = {0.0f, C.y};
#pragma unroll
        for (int k0 = 0; k0 < 4; ++k0) {
            const int k1 = k0 | 4;
            v2f n0r = cv * Sr[k0] - sv * Sr[k1];
            v2f n0i = cv * Si[k0] - sv * Si[k1];
            v2f n1r = sv * Sr[k0] + cv * Sr[k1];
            v2f n1i = sv * Si[k0] + cv * Si[k1];
            Sr[k0] = n0r; Si[k0] = n0i; Sr[k1] = n1r; Si[k1] = n1i;
        }
    }
    {   // e1: ctrl q1 (k bit2), tgt q2 (k bit1)
        const float2 C = *(const float2*)&cs[82];
        ry_pair(Sr[4], Si[4], Sr[6], Si[6], C.x, C.y);
        ry_pair(Sr[5], Si[5], Sr[7], Si[7], C.x, C.y);
    }
    {   // e2: ctrl q2 (k bit1), tgt q3 (k bit0)
        const float2 C = *(const float2*)&cs[84];
        ry_pair(Sr[2], Si[2], Sr[3], Si[3], C.x, C.y);
        ry_pair(Sr[6], Si[6], Sr[7], Si[7], C.x, C.y);
    }
    {   // e3: ctrl q3 (k bit0) -> odd k only; tgt q4 (lane bit5), block form
        const float2 C = *(const float2*)&cs[86];
        const bool hi = (lane >> 5) & 1;
        const float e = hi ? C.y : C.x;
        const float f = hi ? C.x : -C.y;
#pragma unroll
        for (int k = 1; k < 8; k += 2) {
            const VPair R = blkswap2<5>(Sr[k], lane);
            const VPair I = blkswap2<5>(Si[k], lane);
            Sr[k] = e * R.V0 + f * R.V1;
            Si[k] = e * I.V0 + f * I.V1;
        }
    }
    {   // e4: ctrl q4 (lane bit5), tgt q5 (lane bit4), block form
        const float2 C = *(const float2*)&cs[88];
        const bool ctrl = (lane >> 5) & 1;
        const bool hi = (lane >> 4) & 1;
        const float e = ctrl ? (hi ? C.y : C.x) : (hi ? 0.0f : 1.0f);
        const float f = ctrl ? (hi ? C.x : -C.y) : (hi ? 1.0f : 0.0f);
        gate_blk_real<4>(Sr, Si, lane, e, f);
    }
    {   // e5: ctrl lane bit4, tgt lane bit3 (DPP)
        const float2 C = *(const float2*)&cs[90];
        const bool ctrl = (lane >> 4) & 1;
        const float cl = ctrl ? C.x : 1.0f;
        const float sl = ctrl ? C.y : 0.0f;
        const float sgn = ((lane >> 3) & 1) ? sl : -sl;
        gate_dpp_real<3>(Sr, Si, cl, sgn);
    }
    {   // e6: ctrl lane bit3, tgt lane bit2 (swizzle)
        const float2 C = *(const float2*)&cs[92];
        const bool ctrl = (lane >> 3) & 1;
        const float cl = ctrl ? C.x : 1.0f;
        const float sl = ctrl ? C.y : 0.0f;
        const float sgn = ((lane >> 2) & 1) ? sl : -sl;
        gate_dpp_real<2>(Sr, Si, cl, sgn);
    }
    {   // e7: ctrl lane bit2, tgt lane bit1 (DPP)
        const float2 C = *(const float2*)&cs[94];
        const bool ctrl = (lane >> 2) & 1;
        const float cl = ctrl ? C.x : 1.0f;
        const float sl = ctrl ? C.y : 0.0f;
        const float sgn = ((lane >> 1) & 1) ? sl : -sl;
        gate_dpp_real<1>(Sr, Si, cl, sgn);
    }
    {   // e8: ctrl lane bit1, tgt lane bit0 (DPP)
        const float2 C = *(const float2*)&cs[96];
        const bool ctrl = (lane >> 1) & 1;
        const float cl = ctrl ? C.x : 1.0f;
        const float sl = ctrl ? C.y : 0.0f;
        const float sgn = (lane & 1) ? sl : -sl;
        gate_dpp_real<0>(Sr, Si, cl, sgn);
    }

    // ===== F0 = U3_1(0) * CRY_0(9): ctrl q9 (lane bit0), tgt q0 (comp) =====
    {
        LOADM(A, 100); LOADM(Bm, 180);
        const bool ctrl = lane & 1;
        const float M00r = ctrl ? Bm00r : A00r, M00i = ctrl ? Bm00i : A00i;
        const float M01r = ctrl ? Bm01r : A01r, M01i = ctrl ? Bm01i : A01i;
        const float M10r = ctrl ? Bm10r : A10r, M10i = ctrl ? Bm10i : A10i;
        const float M11r = ctrl ? Bm11r : A11r, M11i = ctrl ? Bm11i : A11i;
        const v2f Dr = {M00r, M11r}, Di = {M00i, M11i};
        const v2f Or = {M01r, M10r}, Oi = {M01i, M10i};
#pragma unroll
        for (int k = 0; k < 8; ++k) {
            const v2f Ar = Sr[k], Ai = Si[k];
            const v2f Br = Ar.yx, Bi = Ai.yx;
            Sr[k] = Dr * Ar - Di * Ai + Or * Br - Oi * Bi;
            Si[k] = Dr * Ai + Di * Ar + Or * Bi + Oi * Br;
        }
    }
    // ===== F1 = CRY_1(0) * U3_1(1): ctrl q0 (comp), tgt q1 (k bit2) =====
    {
        LOADM(A, 108); LOADM(Bm, 188);
        const v2f u00r = {A00r, Bm00r}, u00i = {A00i, Bm00i};
        const v2f u01r = {A01r, Bm01r}, u01i = {A01i, Bm01i};
        const v2f u10r = {A10r, Bm10r}, u10i = {A10i, Bm10i};
        const v2f u11r = {A11r, Bm11r}, u11i = {A11i, Bm11i};
#pragma unroll
        for (int k0 = 0; k0 < 4; ++k0) {
            const int k1 = k0 | 4;
            v2f n0r = u00r * Sr[k0] - u00i * Si[k0] + u01r * Sr[k1] - u01i * Si[k1];
            v2f n0i = u00r * Si[k0] + u00i * Sr[k0] + u01r * Si[k1] + u01i * Sr[k1];
            v2f n1r = u10r * Sr[k0] - u10i * Si[k0] + u11r * Sr[k1] - u11i * Si[k1];
            v2f n1i = u10r * Si[k0] + u10i * Sr[k0] + u11r * Si[k1] + u11i * Sr[k1];
            Sr[k0] = n0r; Si[k0] = n0i; Sr[k1] = n1r; Si[k1] = n1i;
        }
    }
    // ===== F2 = CRY_1(1) * U3_1(2): ctrl q1 (k bit2), tgt q2 (k bit1) =====
    {
        LOADM(A, 116); LOADM(Bm, 196);
        u3_pair(Sr[0], Si[0], Sr[2], Si[2], A00r, A00i, A01r, A01i, A10r, A10i, A11r, A11i);
        u3_pair(Sr[1], Si[1], Sr[3], Si[3], A00r, A00i, A01r, A01i, A10r, A10i, A11r, A11i);
        u3_pair(Sr[4], Si[4], Sr[6], Si[6], Bm00r, Bm00i, Bm01r, Bm01i, Bm10r, Bm10i, Bm11r, Bm11i);
        u3_pair(Sr[5], Si[5], Sr[7], Si[7], Bm00r, Bm00i, Bm01r, Bm01i, Bm10r, Bm10i, Bm11r, Bm11i);
    }
    // ===== F3 = CRY_1(2) * U3_1(3): ctrl q2 (k bit1), tgt q3 (k bit0) =====
    {
        LOADM(A, 124); LOADM(Bm, 204);
        u3_pair(Sr[0], Si[0], Sr[1], Si[1], A00r, A00i, A01r, A01i, A10r, A10i, A11r, A11i);
        u3_pair(Sr[4], Si[4], Sr[5], Si[5], A00r, A00i, A01r, A01i, A10r, A10i, A11r, A11i);
        u3_pair(Sr[2], Si[2], Sr[3], Si[3], Bm00r, Bm00i, Bm01r, Bm01i, Bm10r, Bm10i, Bm11r, Bm11i);
        u3_pair(Sr[6], Si[6], Sr[7], Si[7], Bm00r, Bm00i, Bm01r, Bm01i, Bm10r, Bm10i, Bm11r, Bm11i);
    }
    // ===== F4 = CRY_1(3) * U3_1(4): ctrl q3 (k bit0), tgt q4 (lane bit5), block form =====
    {
        LOADM(A, 132); LOADM(Bm, 212);
        const bool hi = (lane >> 5) & 1;
        const float eAr = hi ? A10r : A00r, eAi = hi ? A10i : A00i;
        const float fAr = hi ? A11r : A01r, fAi = hi ? A11i : A01i;
        const float eBr = hi ? Bm10r : Bm00r, eBi = hi ? Bm10i : Bm00i;
        const float fBr = hi ? Bm11r : Bm01r, fBi = hi ? Bm11i : Bm01i;
#pragma unroll
        for (int k = 0; k < 8; ++k) {
            const float er = (k & 1) ? eBr : eAr, ei = (k & 1) ? eBi : eAi;
            const float fr = (k & 1) ? fBr : fAr, fi = (k & 1) ? fBi : fAi;
            const VPair R = blkswap2<5>(Sr[k], lane);
            const VPair I = blkswap2<5>(Si[k], lane);
            Sr[k] = er * R.V0 - ei * I.V0 + fr * R.V1 - fi * I.V1;
            Si[k] = er * I.V0 + ei * R.V0 + fr * I.V1 + fi * R.V1;
        }
    }
    // ===== F5 = CRY_1(4) * U3_1(5): ctrl lane bit5, tgt lane bit4, block form =====
    {
        LOADM(A, 140); LOADM(Bm, 220);
        const bool ctrl = (lane >> 5) & 1;
        const bool hi = (lane >> 4) & 1;
        const float M00r = ctrl ? Bm00r : A00r, M00i = ctrl ? Bm00i : A00i;
        const float M01r = ctrl ? Bm01r : A01r, M01i = ctrl ? Bm01i : A01i;
        const float M10r = ctrl ? Bm10r : A10r, M10i = ctrl ? Bm10i : A10i;
        const float M11r = ctrl ? Bm11r : A11r, M11i = ctrl ? Bm11i : A11i;
        const float er = hi ? M10r : M00r, ei = hi ? M10i : M00i;
        const float fr = hi ? M11r : M01r, fi = hi ? M11i : M01i;
        gate_blk_full<4>(Sr, Si, lane, er, ei, fr, fi);
    }
    // ===== F6..F9: DPP / swizzle lane-bit gates =====
    {
        LOADM(A, 148); LOADM(Bm, 228);       // ctrl bit4, tgt bit3
        const bool ctrl = (lane >> 4) & 1;
        const bool hi = (lane >> 3) & 1;
        const float M00r = ctrl ? Bm00r : A00r, M00i = ctrl ? Bm00i : A00i;
        const float M01r = ctrl ? Bm01r : A01r, M01i = ctrl ? Bm01i : A01i;
        const float M10r = ctrl ? Bm10r : A10r, M10i = ctrl ? Bm10i : A10i;
        const float M11r = ctrl ? Bm11r : A11r, M11i = ctrl ? Bm11i : A11i;
        const float dr = hi ? M11r : M00r, di = hi ? M11i : M00i;
        const float orr = hi ? M10r : M01r, oii = hi ? M10i : M01i;
        gate_dpp_full<3>(Sr, Si, dr, di, orr, oii);
    }
    {
        LOADM(A, 156); LOADM(Bm, 236);       // ctrl bit3, tgt bit2
        const bool ctrl = (lane >> 3) & 1;
        const bool hi = (lane >> 2) & 1;
        const float M00r = ctrl ? Bm00r : A00r, M00i = ctrl ? Bm00i : A00i;
        const float M01r = ctrl ? Bm01r : A01r, M01i = ctrl ? Bm01i : A01i;
        const float M10r = ctrl ? Bm10r : A10r, M10i = ctrl ? Bm10i : A10i;
        const float M11r = ctrl ? Bm11r : A11r, M11i = ctrl ? Bm11i : A11i;
        const float dr = hi ? M11r : M00r, di = hi ? M11i : M00i;
        const float orr = hi ? M10r : M01r, oii = hi ? M10i : M01i;
        gate_dpp_full<2>(Sr, Si, dr, di, orr, oii);
    }
    {
        LOADM(A, 164); LOADM(Bm, 244);       // ctrl bit2, tgt bit1
        const bool ctrl = (lane >> 2) & 1;
        const bool hi = (lane >> 1) & 1;
        const float M00r = ctrl ? Bm00r : A00r, M00i = ctrl ? Bm00i : A00i;
        const float M01r = ctrl ? Bm01r : A01r, M01i = ctrl ? Bm01i : A01i;
        const float M10r = ctrl ? Bm10r : A10r, M10i = ctrl ? Bm10i : A10i;
        const float M11r = ctrl ? Bm11r : A11r, M11i = ctrl ? Bm11i : A11i;
        const float dr = hi ? M11r : M00r, di = hi ? M11i : M00i;
        const float orr = hi ? M10r : M01r, oii = hi ? M10i : M01i;
        gate_dpp_full<1>(Sr, Si, dr, di, orr, oii);
    }
    {
        LOADM(A, 172); LOADM(Bm, 252);       // ctrl bit1, tgt bit0
        const bool ctrl = (lane >> 1) & 1;
        const bool hi = lane & 1;
        const float M00r = ctrl ? Bm00r : A00r, M00i = ctrl ? Bm00i : A00i;
        const float M01r = ctrl ? Bm01r : A01r, M01i = ctrl ? Bm01i : A01i;
        const float M10r = ctrl ? Bm10r : A10r, M10i = ctrl ? Bm10i : A10i;
        const float M11r = ctrl ? Bm11r : A11r, M11i = ctrl ? Bm11i : A11i;
        const float dr = hi ? M11r : M00r, di = hi ? M11i : M00i;
        const float orr = hi ? M10r : M01r, oii = hi ? M10i : M01i;
        gate_dpp_full<0>(Sr, Si, dr, di, orr, oii);
    }
    // ===== CRY_1(9): ctrl q9 (lane bit0), tgt q0 (comp) =====
    {
        const float2 C = *(const float2*)&cs[98];
        const bool ctrl = lane & 1;
        const float cl = ctrl ? C.x : 1.0f;
        const float sl = ctrl ? C.y : 0.0f;
        const v2f C2 = {cl, cl};
        const v2f S2 = {-sl, sl};
#pragma unroll
        for (int k = 0; k < 8; ++k) {
            const v2f Ar = Sr[k], Ai = Si[k];
            Sr[k] = C2 * Ar + S2 * Ar.yx;
            Si[k] = C2 * Ai + S2 * Ai.yx;
        }
    }

    // ===== measurement =====
    v2f P[8];
    float ptot = 0.0f, z0p = 0.0f, z1p = 0.0f, z2p = 0.0f, z3p = 0.0f;
#pragma unroll
    for (int k = 0; k < 8; ++k) {
        P[k] = Sr[k] * Sr[k] + Si[k] * Si[k];
        const float sk = P[k].x + P[k].y;
        ptot += sk;
        z0p += P[k].x - P[k].y;
        z1p += ((k >> 2) & 1) ? -sk : sk;   // qubit1 = k bit2
        z2p += ((k >> 1) & 1) ? -sk : sk;   // qubit2 = k bit1
        z3p += (k & 1) ? -sk : sk;          // qubit3 = k bit0
    }
    // Walsh chain on ptot for lane-bit qubits (qubit q at lane bit 9-q)
    float d0, d1, d2, d3, d4, d5;
    {
        float a = ptot, p;
        p = dppf<0xB1>(a);   d0 = a - p; a += p;
        p = dppf<0x4E>(a);   d1 = a - p; a += p;
        p = swzf<0x101F>(a); d2 = a - p; a += p;
        p = dppf<0x128>(a);  d3 = a - p; a += p;
        { const FPair o = blkswap1<4>(a, lane); d4 = o.v0 - o.v1; a = o.v0 + o.v1; }
        { const FPair o = blkswap1<5>(a, lane); d5 = o.v0 - o.v1; }
    }
    float z[NQ];
    z[0] = plus_reduce<0>(z0p, lane);
    z[1] = plus_reduce<0>(z1p, lane);
    z[2] = plus_reduce<0>(z2p, lane);
    z[3] = plus_reduce<0>(z3p, lane);
    z[4] = d5;                          // lane bit5
    z[5] = plus_reduce<5>(d4, lane);    // lane bit4
    z[6] = plus_reduce<4>(d3, lane);    // lane bit3
    z[7] = plus_reduce<3>(d2, lane);    // lane bit2
    z[8] = plus_reduce<2>(d1, lane);    // lane bit1
    z[9] = plus_reduce<1>(d0, lane);    // lane bit0

    if (lane == 0) {
#pragma unroll
        for (int q = 0; q < NQ; ++q) out[b * NQ + q] = z[q];
    }
}

extern "C" void kernel_launch(void* const* d_in, const int* in_sizes, int n_in,
                              void* d_out, int out_size, void* d_ws, size_t ws_size,
                              hipStream_t stream) {
    const float* inputs  = (const float*)d_in[0];
    const float* weights = (const float*)d_in[1];
    float* out = (float*)d_out;
    const int B = in_sizes[0] / NQ;

    qsim<<<(B + 3) / 4, 256, 0, stream>>>(inputs, weights, out, B);
}